// Round 7
// baseline (153.648 us; speedup 1.0000x reference)
//
#include <hip/hip_runtime.h>
#include <stdint.h>

#define L_SEQ 4096
#define D_MODEL 1024
#define HEAD 64
#define KCH 256         // kv per chunk (<=4 stages of 64)
#define MAXCH 16
#define NQT 32          // 128-row q tiles
#define NSLOT 272       // sum over qt of nch(qt) = ceil((qt+1)/2)

typedef unsigned short u16;
typedef _Float16 f16;
typedef __attribute__((ext_vector_type(8))) f16 f16x8;
typedef __attribute__((ext_vector_type(2))) __fp16 fp16x2;
typedef __attribute__((ext_vector_type(4))) float f32x4;

static __device__ __forceinline__ u16 f16bits(float f) {
    union { f16 h; u16 u; } c; c.h = (f16)f; return c.u;
}
static __device__ __forceinline__ uint32_t pk16(float a, float b) {
    union { fp16x2 h; uint32_t u; } c;
    c.h = __builtin_amdgcn_cvt_pkrtz(a, b);
    return c.u;
}
static __device__ __forceinline__ f16x8 ld8h(const u16* p) { return *(const f16x8*)p; }

static __device__ __forceinline__ f32x4 mfma16h(f16x8 a, f16x8 b, f32x4 c) {
    return __builtin_amdgcn_mfma_f32_16x16x32_f16(a, b, c, 0, 0, 0);
}

// async global->LDS, 16B per lane, fire-and-forget (cannot be sunk)
static __device__ __forceinline__ void gload16(const u16* g, u16* l) {
    __builtin_amdgcn_global_load_lds(
        (const __attribute__((address_space(1))) void*)g,
        (__attribute__((address_space(3))) void*)l, 16, 0, 0);
}

// slot prefix for KCH=256: nch(qt) = (qt+2)>>1; Sq(qt) = sum_{k<qt} nch(k)
// closed form: f=qt>>1, r=qt&1 -> (f+1)*(f+r). Sq(32)=272=NSLOT.
static __device__ __forceinline__ int Sq(int qt) {
    int f = qt >> 1, r = qt & 1;
    return (f + 1) * (f + r);
}

// --- Kernel 0: W fp32 [1024,64] -> f16 Wt [64,1024] x3; Wq scaled log2e/8
__global__ __launch_bounds__(256) void conv_w(
    const float* __restrict__ Wq, const float* __restrict__ Wk,
    const float* __restrict__ Wv, u16* __restrict__ Wt)
{
    __shared__ u16 tile[64][72];
    const float* W = (blockIdx.y == 0) ? Wq : (blockIdx.y == 1) ? Wk : Wv;
    const float sc = (blockIdx.y == 0) ? 0.18033688f : 1.0f;  // log2(e)/8
    u16* dst = Wt + blockIdx.y * (HEAD * D_MODEL);
    const int k0 = blockIdx.x * 64, t = threadIdx.x;
    #pragma unroll
    for (int i = 0; i < 16; i++) {
        int idx = i * 256 + t;
        int kk = idx >> 6, h = idx & 63;
        tile[h][kk] = f16bits(W[(size_t)(k0 + kk) * HEAD + h] * sc);
    }
    __syncthreads();
    #pragma unroll
    for (int i = 0; i < 16; i++) {
        int idx = i * 256 + t;
        int h = idx >> 6, kk = idx & 63;
        dst[(size_t)h * D_MODEL + k0 + kk] = tile[h][kk];
    }
}

// --- Kernel 1: QKV projection, T14 register-staged W prefetch (round-4 form;
// round-6 swizzle reverted: 64B-row-stride bank geometry makes XOR a no-op).
__global__ __launch_bounds__(256, 4) void qkv_proj(
    const float* __restrict__ x, const u16* __restrict__ Wt,
    u16* __restrict__ qb, u16* __restrict__ kb, u16* __restrict__ vTb)
{
    __shared__ __align__(16) u16 Wl[2 * 192 * 32];   // 24576 B [dh][192][32]
    __shared__ __align__(16) u16 Xl[2 * 32 * 36];    // 4608 B  [kh][32][36]
#define WLX(dh,r,c) Wl[((dh)*192 + (r))*32 + (c)]
#define XLX(kh,r,c) Xl[((kh)*32  + (r))*36 + (c)]
#define CT(r,c)     Wl[(r)*200 + (c)]               // epilogue overlay

    const int t = threadIdx.x;
    const int wv = t >> 6, lane = t & 63;
    const int ln16 = lane & 15, quad = lane >> 4;
    const int w3 = wv * 3;
    const int m0 = blockIdx.x * 32;

    f32x4 acc[2][3] = {};
    float4 xv0, xv1;
    f16x8 wreg[6];     // 24 VGPRs: this wave's 6 x 1KB W units of next stage

    auto loadW = [&](int s) {
        const int k0 = s * 64;
        #pragma unroll
        for (int k2 = 0; k2 < 6; k2++) {
            int c = wv * 6 + k2;
            int dh = c & 1, g = c >> 1;
            wreg[k2] = ld8h(Wt + (size_t)(g * 16 + (lane >> 2)) * D_MODEL
                               + k0 + dh * 32 + (lane & 3) * 8);
        }
    };
    auto writeW = [&]() {
        #pragma unroll
        for (int k2 = 0; k2 < 6; k2++) {
            int c = wv * 6 + k2;
            int dh = c & 1, g = c >> 1;
            *(f16x8*)&WLX(dh, g * 16 + (lane >> 2), (lane & 3) * 8) = wreg[k2];
        }
    };
    auto loadx = [&](int s) {
        const int k0 = s * 64;
        int r0 = t >> 4, cs0 = (t & 15) * 4;
        xv0 = *(const float4*)&x[(size_t)(m0 + r0) * D_MODEL + k0 + cs0];
        int idx = 256 + t, r1 = idx >> 4, cs1 = (idx & 15) * 4;
        xv1 = *(const float4*)&x[(size_t)(m0 + r1) * D_MODEL + k0 + cs1];
    };
    auto packx = [&]() {
        int r0 = t >> 4, cs0 = (t & 15) * 4;
        uint2 p0; p0.x = pk16(xv0.x, xv0.y); p0.y = pk16(xv0.z, xv0.w);
        *(uint2*)&XLX(cs0 >> 5, r0, cs0 & 31) = p0;
        int idx = 256 + t, r1 = idx >> 4, cs1 = (idx & 15) * 4;
        uint2 p1; p1.x = pk16(xv1.x, xv1.y); p1.y = pk16(xv1.z, xv1.w);
        *(uint2*)&XLX(cs1 >> 5, r1, cs1 & 31) = p1;
    };

    loadW(0); loadx(0); writeW(); packx();
    for (int s = 0; s < 16; s++) {
        __syncthreads();          // stage-s W ds_writes + x LDS writes visible
        if (s + 1 < 16) { loadW(s + 1); loadx(s + 1); }  // hide under MFMA
        #pragma unroll
        for (int c = 0; c < 2; c++) {
            f16x8 xb0 = ld8h(&XLX(c, ln16, quad * 8));
            f16x8 xb1 = ld8h(&XLX(c, 16 + ln16, quad * 8));
            #pragma unroll
            for (int j = 0; j < 3; j++) {
                f16x8 af = ld8h(&WLX(c, (w3 + j) * 16 + ln16, quad * 8));
                acc[0][j] = mfma16h(af, xb0, acc[0][j]);
                acc[1][j] = mfma16h(af, xb1, acc[1][j]);
            }
        }
        __syncthreads();          // all LDS reads of stage s complete
        if (s + 1 < 16) { writeW(); packx(); }
    }

    __syncthreads();   // overlay Ct on W region
    #pragma unroll
    for (int mt = 0; mt < 2; mt++) {
        #pragma unroll
        for (int j = 0; j < 3; j++) {
            int g0 = (w3 + j) * 16 + quad * 4;
            uint2 pk;
            pk.x = pk16(acc[mt][j][0], acc[mt][j][1]);
            pk.y = pk16(acc[mt][j][2], acc[mt][j][3]);
            *(uint2*)&CT(mt * 16 + ln16, g0) = pk;
        }
    }
    __syncthreads();
    {
        int m = t >> 3, hg = (t & 7) * 8;
        *(f16x8*)&qb[(size_t)(m0 + m) * HEAD + hg] = *(f16x8*)&CT(m, hg);
        *(f16x8*)&kb[(size_t)(m0 + m) * HEAD + hg] = *(f16x8*)&CT(m, 64 + hg);
        int h = t >> 2, mg = (t & 3) * 8;
        f16x8 vvv;
        #pragma unroll
        for (int jj = 0; jj < 8; jj++)
            ((u16*)&vvv)[jj] = CT(mg + jj, 128 + h);
        int bbt = m0 >> 12, l0 = m0 & 4095;
        *(f16x8*)&vTb[(size_t)(bbt * HEAD + h) * L_SEQ + l0 + mg] = vvv;
    }
#undef WLX
#undef XLX
#undef CT
}

// --- Kernel 2: split-KV causal attention, KCH=256 for TLP.
// Old grid: 576 blocks = 2.25 blk/CU = 9 waves/CU (grid-limited, NOT LDS-
// limited) -> every pipe <40% busy yet attn latency-bound. New: 1088 blocks
// (17 waves/CU): exactly 1024 UNIFORM full 4-stage chunks (4/CU under any
// dispatch model) + 64 two-stage tails that backfill. Inner loop = round-5.
__global__ __launch_bounds__(256, 4) void attn_chunk(
    const u16* __restrict__ qb, const u16* __restrict__ kb,
    const u16* __restrict__ vT, float* __restrict__ Opart, float* __restrict__ lpart,
    float* __restrict__ out)
{
    // ---- id -> (b, qt, ch): ids 0-1023 full 4-stage chunks (uniform),
    //      ids 1024-1087 the 2-stage tails of even qt (incl qt=0 direct).
    const int id = blockIdx.x;
    const int b = id & 3;
    int qt, ch;
    if (id < 1024) {
        int fi = id >> 2;               // 0..255; fulls(qt) = (qt+1)>>1
        int acc = 0;
        qt = 31; ch = 0;
        #pragma unroll
        for (int k = 0; k < 32; k++) {
            int nf = (k + 1) >> 1;
            if (fi < acc + nf) { qt = k; ch = fi - acc; break; }
            acc += nf;
        }
    } else {
        int li = (id - 1024) >> 2;      // 0..15
        qt = 2 * li; ch = li;           // tail chunk of even qt (128 kv)
    }

    __shared__ __align__(16) u16 Kls[2 * 64 * 32];   // 8 KB  [dh][64][32]
    __shared__ __align__(16) u16 Vls[2 * 64 * 32];   // 8 KB  [kh][64][32]
    __shared__ __align__(16) u16 Pls[4 * 32 * 72];   // 18 KB wave-private P
#define KBX(dh,r,c) Kls[((dh)*64 + (r))*32 + (c)]
#define VBX(kh,r,c) Vls[((kh)*64 + (r))*32 + (c)]
#define PX(r,c)     Pls[((wv)*32 + (r))*72 + (c)]

    const int t = threadIdx.x, wv = t >> 6, lane = t & 63;
    const int ln16 = lane & 15, quad = lane >> 4;
    const int qmin = qt * 128 + wv * 32;
    const int nch = (qt + 2) >> 1;      // ceil((qt+1)*128 / 256)

    // Q as B-operand: B[k=d=quad*8+j][n=q=ln16]; q pre-scaled log2e/8 via Wq
    f16x8 qf[2][2];
    #pragma unroll
    for (int qn = 0; qn < 2; qn++) {
        const u16* qrp = qb + (size_t)(b * L_SEQ + qmin + qn * 16 + ln16) * HEAD + quad * 8;
        qf[qn][0] = ld8h(qrp); qf[qn][1] = ld8h(qrp + 32);
    }

    const u16* kbb = kb + (size_t)b * L_SEQ * HEAD;
    const u16* vbb = vT + (size_t)b * HEAD * L_SEQ;

    f32x4 o[2][4] = {};            // O^T[h=hg*16+quad*4+r][q=qn*16+ln16]
    float lsum[2] = {0.f, 0.f};

    const int kv_lo = ch * KCH;
    const int kv_hi = min(kv_lo + KCH, qt * 128 + 128);
    const int nst = (kv_hi - kv_lo) >> 6;

    // 8 K-load units (dh x g) over 4 waves, 2 each; same for V
    auto issueK = [&](int kv0) {
        #pragma unroll
        for (int k2 = 0; k2 < 2; k2++) {
            int c = wv * 2 + k2;
            int dh = c & 1, g = c >> 1;
            const u16* gp = kbb + (size_t)(kv0 + g * 16 + (lane >> 2)) * HEAD
                                + dh * 32 + (lane & 3) * 8;
            gload16(gp, &KBX(dh, g * 16 + (lane >> 2), (lane & 3) * 8));
        }
    };
    auto issueV = [&](int kv0) {
        #pragma unroll
        for (int k2 = 0; k2 < 2; k2++) {
            int c = wv * 2 + k2;
            int kh = c & 1, g = c >> 1;
            const u16* gp = vbb + (size_t)(g * 16 + (lane >> 2)) * L_SEQ
                                + kv0 + kh * 32 + (lane & 3) * 8;
            gload16(gp, &VBX(kh, g * 16 + (lane >> 2), (lane & 3) * 8));
        }
    };

    issueK(kv_lo); issueV(kv_lo);
    __syncthreads();                   // prologue: stage 0 resident

    for (int s = 0; s < nst; s++) {
        const int kv0 = kv_lo + s * 64;

        // --- QK phase: reads Kls + qf, writes wave-private P ---
        #pragma unroll
        for (int g = 0; g < 4; g++) {
            f16x8 ka0 = ld8h(&KBX(0, g * 16 + ln16, quad * 8));
            f16x8 ka1 = ld8h(&KBX(1, g * 16 + ln16, quad * 8));
            #pragma unroll
            for (int qn = 0; qn < 2; qn++) {
                f32x4 s2 = {};
                s2 = mfma16h(ka0, qf[qn][0], s2);
                s2 = mfma16h(ka1, qf[qn][1], s2);
                // S^T[kv=kv0+g*16+quad*4+r][q=qmin+qn*16+ln16]; p = 2^s
                float p0, p1, p2, p3;
                if (kv0 + g * 16 + 15 <= qmin + qn * 16) {     // fully unmasked
                    p0 = __builtin_amdgcn_exp2f(s2[0]);
                    p1 = __builtin_amdgcn_exp2f(s2[1]);
                    p2 = __builtin_amdgcn_exp2f(s2[2]);
                    p3 = __builtin_amdgcn_exp2f(s2[3]);
                } else {
                    int q = qmin + qn * 16 + ln16;
                    int kv = kv0 + g * 16 + quad * 4;
                    p0 = (kv     <= q) ? __builtin_amdgcn_exp2f(s2[0]) : 0.f;
                    p1 = (kv + 1 <= q) ? __builtin_amdgcn_exp2f(s2[1]) : 0.f;
                    p2 = (kv + 2 <= q) ? __builtin_amdgcn_exp2f(s2[2]) : 0.f;
                    p3 = (kv + 3 <= q) ? __builtin_amdgcn_exp2f(s2[3]) : 0.f;
                }
                lsum[qn] += (p0 + p1) + (p2 + p3);
                uint2 pk; pk.x = pk16(p0, p1); pk.y = pk16(p2, p3);
                *(uint2*)&PX(qn * 16 + ln16, g * 16 + quad * 4) = pk;
            }
        }

        __syncthreads();               // all waves done reading K(s)
        if (s + 1 < nst) issueK(kv0 + 64);   // K(s+1) overlaps PV below

        // --- PV phase: reads wave-private P (same-wave lgkm order) + Vls ---
        f16x8 pf[2][2];
        #pragma unroll
        for (int qn = 0; qn < 2; qn++) {
            pf[qn][0] = ld8h(&PX(qn * 16 + ln16, quad * 8));
            pf[qn][1] = ld8h(&PX(qn * 16 + ln16, 32 + quad * 8));
        }
        #pragma unroll
        for (int hg = 0; hg < 4; hg++) {
            f16x8 va0 = ld8h(&VBX(0, hg * 16 + ln16, quad * 8));
            f16x8 va1 = ld8h(&VBX(1, hg * 16 + ln16, quad * 8));
            #pragma unroll
            for (int qn = 0; qn < 2; qn++) {
                o[qn][hg] = mfma16h(va0, pf[qn][0], o[qn][hg]);
                o[qn][hg] = mfma16h(va1, pf[qn][1], o[qn][hg]);
            }
        }

        __syncthreads();               // all waves done reading V(s); K(s+1) drained
        if (s + 1 < nst) issueV(kv0 + 64);   // V(s+1) overlaps next QK phase
    }

    #pragma unroll
    for (int qn = 0; qn < 2; qn++) {
        lsum[qn] += __shfl_xor(lsum[qn], 16);
        lsum[qn] += __shfl_xor(lsum[qn], 32);
    }

    if (nch == 1) {
        // qt 0/1: single chunk -> final result (path verified in round 2)
        #pragma unroll
        for (int qn = 0; qn < 2; qn++) {
            float inv = 1.f / lsum[qn];
            int q = qmin + qn * 16 + ln16;
            #pragma unroll
            for (int hg = 0; hg < 4; hg++) {
                float4 r;
                r.x = o[qn][hg][0] * inv; r.y = o[qn][hg][1] * inv;
                r.z = o[qn][hg][2] * inv; r.w = o[qn][hg][3] * inv;
                *(float4*)&out[((size_t)(b * L_SEQ + q)) * HEAD + hg * 16 + quad * 4] = r;
            }
        }
        return;
    }

    const size_t base = (size_t)(b * NSLOT + Sq(qt) + ch);
    #pragma unroll
    for (int qn = 0; qn < 2; qn++) {
        int q_local = wv * 32 + qn * 16 + ln16;
        #pragma unroll
        for (int hg = 0; hg < 4; hg++)
            *(f32x4*)&Opart[base * 8192 + (size_t)q_local * 64 + hg * 16 + quad * 4] = o[qn][hg];
        if (quad == 0)
            lpart[base * 128 + q_local] = lsum[qn];
    }
#undef KBX
#undef VBX
#undef PX
}

// --- Kernel 3: merge partials for qt >= 2 (qt 0/1 are single-chunk, written
// directly by attn_chunk). <=16 chunks, scalar-branch-guarded loads.
__global__ __launch_bounds__(256) void merge_chunks(
    const float* __restrict__ Opart, const float* __restrict__ lpart,
    float* __restrict__ out)
{
    const int qt = blockIdx.x + 2, qseg = blockIdx.y, b = blockIdx.z;
    const int nch = (qt + 2) >> 1;
    const int t = threadIdx.x;
    const size_t obase = (size_t)(b * NSLOT + Sq(qt)) * 8192;
    const size_t lbase = (size_t)(b * NSLOT + Sq(qt)) * 128;
    #pragma unroll
    for (int i = 0; i < 2; i++) {
        int idx = i * 256 + t;              // 32 q x 16 h-groups
        int q = qseg * 32 + (idx >> 4), hg = (idx & 15) * 4;
        float L = 0.f, ax = 0.f, ay = 0.f, az = 0.f, aw = 0.f;
        #pragma unroll
        for (int c = 0; c < MAXCH; c++) {
            if (c < nch) {                  // block-uniform scalar branch
                L += lpart[lbase + c * 128 + q];
                const float4 v = *(const float4*)&Opart[obase + (size_t)c * 8192 + q * 64 + hg];
                ax += v.x; ay += v.y; az += v.z; aw += v.w;
            }
        }
        float inv = 1.f / L;
        float4 r; r.x = ax * inv; r.y = ay * inv; r.z = az * inv; r.w = aw * inv;
        *(float4*)&out[((size_t)(b * L_SEQ + qt * 128 + q)) * HEAD + hg] = r;
    }
}

extern "C" void kernel_launch(void* const* d_in, const int* in_sizes, int n_in,
                              void* d_out, int out_size, void* d_ws, size_t ws_size,
                              hipStream_t stream) {
    const float* x  = (const float*)d_in[0];
    const float* Wq = (const float*)d_in[1];
    const float* Wk = (const float*)d_in[2];
    const float* Wv = (const float*)d_in[3];
    float* out = (float*)d_out;

    u16* ws16 = (u16*)d_ws;
    u16* Wt  = ws16;                          // [192][1024] f16 (q|k|v rows)
    u16* qb  = Wt + 3 * HEAD * D_MODEL;       // [4,4096,64] f16
    u16* kb  = qb + 16384 * HEAD;
    u16* vTb = kb + 16384 * HEAD;             // [4,64,4096] f16
    float* Opart = (float*)(vTb + 16384 * HEAD);     // [4*272][8192] f32 = 35.7 MB
    float* lpart = Opart + (size_t)4 * NSLOT * 8192; // [4*272][128] f32

    conv_w      <<<dim3(16, 3), 256, 0, stream>>>(Wq, Wk, Wv, Wt);
    qkv_proj    <<<dim3(512), 256, 0, stream>>>(x, Wt, qb, kb, vTb);
    attn_chunk  <<<dim3(1088), 256, 0, stream>>>(qb, kb, vTb, Opart, lpart, out);
    merge_chunks<<<dim3(NQT - 2, 4, 4), 256, 0, stream>>>(Opart, lpart, out);
}

// Round 8
// 143.991 us; speedup vs baseline: 1.0671x; 1.0671x over previous
//
#include <hip/hip_runtime.h>
#include <stdint.h>

#define L_SEQ 4096
#define D_MODEL 1024
#define HEAD 64
#define KCH 512         // kv per chunk (<=4 stages of 128)
#define MAXCH 8
#define NQT 32          // 128-row q tiles

typedef unsigned short u16;
typedef _Float16 f16;
typedef __attribute__((ext_vector_type(8))) f16 f16x8;
typedef __attribute__((ext_vector_type(2))) __fp16 fp16x2;
typedef __attribute__((ext_vector_type(4))) float f32x4;

static __device__ __forceinline__ u16 f16bits(float f) {
    union { f16 h; u16 u; } c; c.h = (f16)f; return c.u;
}
static __device__ __forceinline__ uint32_t pk16(float a, float b) {
    union { fp16x2 h; uint32_t u; } c;
    c.h = __builtin_amdgcn_cvt_pkrtz(a, b);
    return c.u;
}
static __device__ __forceinline__ f16x8 ld8h(const u16* p) { return *(const f16x8*)p; }

static __device__ __forceinline__ f32x4 mfma16h(f16x8 a, f16x8 b, f32x4 c) {
    return __builtin_amdgcn_mfma_f32_16x16x32_f16(a, b, c, 0, 0, 0);
}

// async global->LDS, 16B per lane, fire-and-forget (cannot be sunk)
static __device__ __forceinline__ void gload16(const u16* g, u16* l) {
    __builtin_amdgcn_global_load_lds(
        (const __attribute__((address_space(1))) void*)g,
        (__attribute__((address_space(3))) void*)l, 16, 0, 0);
}

// compacted slot prefix: Sq(qt) = sum_{k<qt} ceil((k+1)/4); total Sq(32)=144
static __device__ __forceinline__ int Sq(int qt) {
    int f = qt >> 2, r = qt & 3;
    return (f + 1) * (2 * f + r);
}

// --- Kernel 0: W fp32 [1024,64] -> f16 Wt [64,1024] x3; Wq scaled log2e/8
__global__ __launch_bounds__(256) void conv_w(
    const float* __restrict__ Wq, const float* __restrict__ Wk,
    const float* __restrict__ Wv, u16* __restrict__ Wt)
{
    __shared__ u16 tile[64][72];
    const float* W = (blockIdx.y == 0) ? Wq : (blockIdx.y == 1) ? Wk : Wv;
    const float sc = (blockIdx.y == 0) ? 0.18033688f : 1.0f;  // log2(e)/8
    u16* dst = Wt + blockIdx.y * (HEAD * D_MODEL);
    const int k0 = blockIdx.x * 64, t = threadIdx.x;
    #pragma unroll
    for (int i = 0; i < 16; i++) {
        int idx = i * 256 + t;
        int kk = idx >> 6, h = idx & 63;
        tile[h][kk] = f16bits(W[(size_t)(k0 + kk) * HEAD + h] * sc);
    }
    __syncthreads();
    #pragma unroll
    for (int i = 0; i < 16; i++) {
        int idx = i * 256 + t;
        int h = idx >> 6, kk = idx & 63;
        dst[(size_t)h * D_MODEL + k0 + kk] = tile[h][kk];
    }
}

// --- Kernel 1: QKV projection, BK=128 (8 fat stages). Grid-capped at
// 2 blk/CU, so growing LDS to 57KB costs no occupancy; barrier pairs
// halve (16->8) and each pair now covers 24 MFMA. W reg-staged (T14).
// k-chunk accumulation order unchanged -> bitwise-identical output.
__global__ __launch_bounds__(256, 2) void qkv_proj(
    const float* __restrict__ x, const u16* __restrict__ Wt,
    u16* __restrict__ qb, u16* __restrict__ kb, u16* __restrict__ vTb)
{
    __shared__ __align__(16) u16 Wl[4 * 192 * 32];   // 49152 B [dh4][192][32]
    __shared__ __align__(16) u16 Xl[4 * 32 * 36];    // 9216 B  [kh4][32][36]
#define WLX(dh,r,c) Wl[((dh)*192 + (r))*32 + (c)]
#define XLX(kh,r,c) Xl[((kh)*32  + (r))*36 + (c)]
#define CT(r,c)     Wl[(r)*200 + (c)]               // epilogue overlay

    const int t = threadIdx.x;
    const int wv = t >> 6, lane = t & 63;
    const int ln16 = lane & 15, quad = lane >> 4;
    const int w3 = wv * 3;
    const int m0 = blockIdx.x * 32;
    const int r4 = lane >> 2, cl8 = (lane & 3) * 8;

    f32x4 acc[2][3] = {};
    float4 xv0, xv1, xv2, xv3;
    f16x8 wreg[12];    // 48 VGPRs: this wave's 12 x 1KB W units of next stage

    // 48 units: dh(4 col-blocks of 32) x g(12 row-blocks of 16); 12/wave
    auto loadW = [&](int s) {
        const int k0 = s * 128;
        #pragma unroll
        for (int k2 = 0; k2 < 12; k2++) {
            int c = wv * 12 + k2;
            int dh = c & 3, g = c >> 2;
            wreg[k2] = ld8h(Wt + (size_t)(g * 16 + r4) * D_MODEL
                               + k0 + dh * 32 + cl8);
        }
    };
    auto writeW = [&]() {
        #pragma unroll
        for (int k2 = 0; k2 < 12; k2++) {
            int c = wv * 12 + k2;
            int dh = c & 3, g = c >> 2;
            *(f16x8*)&WLX(dh, g * 16 + r4, cl8) = wreg[k2];
        }
    };
    // x: 32 rows x 128 f32 per stage = 4 float4/thread; col fixed per thread
    const int xc4 = (t & 31) * 4;          // f32 col 0..124
    const int xr0 = t >> 5;                // row base 0..7, rows step 8
    auto loadx = [&](int s) {
        const int k0 = s * 128;
        const float* xp = &x[(size_t)(m0 + xr0) * D_MODEL + k0 + xc4];
        xv0 = *(const float4*)(xp);
        xv1 = *(const float4*)(xp +  8 * D_MODEL);
        xv2 = *(const float4*)(xp + 16 * D_MODEL);
        xv3 = *(const float4*)(xp + 24 * D_MODEL);
    };
    auto packx = [&]() {
        const int kh = xc4 >> 5, ci = xc4 & 31;
        uint2 p;
        p.x = pk16(xv0.x, xv0.y); p.y = pk16(xv0.z, xv0.w);
        *(uint2*)&XLX(kh, xr0,      ci) = p;
        p.x = pk16(xv1.x, xv1.y); p.y = pk16(xv1.z, xv1.w);
        *(uint2*)&XLX(kh, xr0 +  8, ci) = p;
        p.x = pk16(xv2.x, xv2.y); p.y = pk16(xv2.z, xv2.w);
        *(uint2*)&XLX(kh, xr0 + 16, ci) = p;
        p.x = pk16(xv3.x, xv3.y); p.y = pk16(xv3.z, xv3.w);
        *(uint2*)&XLX(kh, xr0 + 24, ci) = p;
    };

    loadW(0); loadx(0); writeW(); packx();
    for (int s = 0; s < 8; s++) {
        __syncthreads();          // stage-s W ds_writes + x LDS writes visible
        if (s + 1 < 8) { loadW(s + 1); loadx(s + 1); }  // hide under MFMA
        #pragma unroll
        for (int c = 0; c < 4; c++) {
            f16x8 xb0 = ld8h(&XLX(c, ln16, quad * 8));
            f16x8 xb1 = ld8h(&XLX(c, 16 + ln16, quad * 8));
            #pragma unroll
            for (int j = 0; j < 3; j++) {
                f16x8 af = ld8h(&WLX(c, (w3 + j) * 16 + ln16, quad * 8));
                acc[0][j] = mfma16h(af, xb0, acc[0][j]);
                acc[1][j] = mfma16h(af, xb1, acc[1][j]);
            }
        }
        __syncthreads();          // all LDS reads of stage s complete
        if (s + 1 < 8) { writeW(); packx(); }
    }

    __syncthreads();   // overlay Ct on W region
    #pragma unroll
    for (int mt = 0; mt < 2; mt++) {
        #pragma unroll
        for (int j = 0; j < 3; j++) {
            int g0 = (w3 + j) * 16 + quad * 4;
            uint2 pk;
            pk.x = pk16(acc[mt][j][0], acc[mt][j][1]);
            pk.y = pk16(acc[mt][j][2], acc[mt][j][3]);
            *(uint2*)&CT(mt * 16 + ln16, g0) = pk;
        }
    }
    __syncthreads();
    {
        int m = t >> 3, hg = (t & 7) * 8;
        *(f16x8*)&qb[(size_t)(m0 + m) * HEAD + hg] = *(f16x8*)&CT(m, hg);
        *(f16x8*)&kb[(size_t)(m0 + m) * HEAD + hg] = *(f16x8*)&CT(m, 64 + hg);
        int h = t >> 2, mg = (t & 3) * 8;
        f16x8 vvv;
        #pragma unroll
        for (int jj = 0; jj < 8; jj++)
            ((u16*)&vvv)[jj] = CT(mg + jj, 128 + h);
        int bbt = m0 >> 12, l0 = m0 & 4095;
        *(f16x8*)&vTb[(size_t)(bbt * HEAD + h) * L_SEQ + l0 + mg] = vvv;
    }
#undef WLX
#undef XLX
#undef CT
}

// --- Kernel 2: split-KV causal attention, round-5 balanced 576-block grid,
// stage fattened to 128 kv (two 64-row halves; P reused h0->h1 wave-private).
// Barrier pairs per chunk halve; round-5 overlap kept:
//   QKh0 -> PVh0 -> QKh1 -> bar -> issueK(s+1) -> PVh1 -> bar -> issueV(s+1)
// LDS 50 KB -> 3 blk/CU cap >= grid's 2.25 avg (occupancy-free fattening).
__global__ __launch_bounds__(256, 3) void attn_chunk(
    const u16* __restrict__ qb, const u16* __restrict__ kb,
    const u16* __restrict__ vT, float* __restrict__ Opart, float* __restrict__ lpart,
    float* __restrict__ out)
{
    // ---- id -> (b, qt, ch), heavy-first ordering (round-5 mapping) ----
    const int id = blockIdx.x;
    const int b = id & 3;
    int qt, ch;
    if (id < 480) {
        int fi = id >> 2;
        int acc = 0;
        qt = 31; ch = 0;
        #pragma unroll
        for (int k = 0; k < 32; k++) {
            int nf = (k + 1) >> 2;          // full chunks of qt=k
            if (fi < acc + nf) { qt = k; ch = fi - acc; break; }
            acc += nf;
        }
    } else {
        int pi = (id - 480) >> 2;
        int m = pi & 7;
        qt = (pi < 8) ? (4 * m + 2) : (pi < 16) ? (4 * m + 1) : (4 * m);
        ch = m;
    }

    __shared__ __align__(16) u16 Kls[4 * 64 * 32];   // 16 KB [hf][dh][64][32]
    __shared__ __align__(16) u16 Vls[4 * 64 * 32];   // 16 KB [hf][kh][64][32]
    __shared__ __align__(16) u16 Pls[4 * 32 * 72];   // 18 KB wave-private P
#define KBX(hf,dh,r,c) Kls[((((hf)*2+(dh))*64) + (r))*32 + (c)]
#define VBX(hf,kh,r,c) Vls[((((hf)*2+(kh))*64) + (r))*32 + (c)]
#define PX(r,c)        Pls[((wv)*32 + (r))*72 + (c)]

    const int t = threadIdx.x, wv = t >> 6, lane = t & 63;
    const int ln16 = lane & 15, quad = lane >> 4;
    const int qmin = qt * 128 + wv * 32;
    const int nch = (qt + 4) >> 2;      // ceil((qt+1)/4) active chunks
    const int r4 = lane >> 2, cl8 = (lane & 3) * 8;

    // Q as B-operand: B[k=d=quad*8+j][n=q=ln16]; q pre-scaled log2e/8 via Wq
    f16x8 qf[2][2];
    #pragma unroll
    for (int qn = 0; qn < 2; qn++) {
        const u16* qrp = qb + (size_t)(b * L_SEQ + qmin + qn * 16 + ln16) * HEAD + quad * 8;
        qf[qn][0] = ld8h(qrp); qf[qn][1] = ld8h(qrp + 32);
    }

    const u16* kbb = kb + (size_t)b * L_SEQ * HEAD;
    const u16* vbb = vT + (size_t)b * HEAD * L_SEQ;

    f32x4 o[2][4] = {};            // O^T[h=hg*16+quad*4+r][q=qn*16+ln16]
    float lsum[2] = {0.f, 0.f};

    const int kv_lo = ch * KCH;
    const int kv_hi = min(kv_lo + KCH, qt * 128 + 128);
    const int nst = (kv_hi - kv_lo) >> 7;   // 128-kv stages; spans % 128 == 0

    // 16 K units (hf x dh x g) over 4 waves, 4 each; same for V
    auto issueK = [&](int kv0) {
        #pragma unroll
        for (int k2 = 0; k2 < 4; k2++) {
            int c = wv * 4 + k2;
            int dh = c & 1, g = (c >> 1) & 3, hf = c >> 3;
            const u16* gp = kbb + (size_t)(kv0 + hf * 64 + g * 16 + r4) * HEAD
                                + dh * 32 + cl8;
            gload16(gp, &KBX(hf, dh, g * 16 + r4, cl8));
        }
    };
    auto issueV = [&](int kv0) {
        #pragma unroll
        for (int k2 = 0; k2 < 4; k2++) {
            int c = wv * 4 + k2;
            int kh = c & 1, g = (c >> 1) & 3, hf = c >> 3;
            const u16* gp = vbb + (size_t)(g * 16 + r4) * L_SEQ
                                + kv0 + hf * 64 + kh * 32 + cl8;
            gload16(gp, &VBX(hf, kh, g * 16 + r4, cl8));
        }
    };

    // QK on half hf at absolute base kv0h; writes wave-private P
    auto qk_half = [&](int hf, int kv0h) {
        #pragma unroll
        for (int g = 0; g < 4; g++) {
            f16x8 ka0 = ld8h(&KBX(hf, 0, g * 16 + ln16, quad * 8));
            f16x8 ka1 = ld8h(&KBX(hf, 1, g * 16 + ln16, quad * 8));
            #pragma unroll
            for (int qn = 0; qn < 2; qn++) {
                f32x4 s2 = {};
                s2 = mfma16h(ka0, qf[qn][0], s2);
                s2 = mfma16h(ka1, qf[qn][1], s2);
                // S^T[kv=kv0h+g*16+quad*4+r][q=qmin+qn*16+ln16]; p = 2^s
                float p0, p1, p2, p3;
                if (kv0h + g * 16 + 15 <= qmin + qn * 16) {    // fully unmasked
                    p0 = __builtin_amdgcn_exp2f(s2[0]);
                    p1 = __builtin_amdgcn_exp2f(s2[1]);
                    p2 = __builtin_amdgcn_exp2f(s2[2]);
                    p3 = __builtin_amdgcn_exp2f(s2[3]);
                } else {
                    int q = qmin + qn * 16 + ln16;
                    int kv = kv0h + g * 16 + quad * 4;
                    p0 = (kv     <= q) ? __builtin_amdgcn_exp2f(s2[0]) : 0.f;
                    p1 = (kv + 1 <= q) ? __builtin_amdgcn_exp2f(s2[1]) : 0.f;
                    p2 = (kv + 2 <= q) ? __builtin_amdgcn_exp2f(s2[2]) : 0.f;
                    p3 = (kv + 3 <= q) ? __builtin_amdgcn_exp2f(s2[3]) : 0.f;
                }
                lsum[qn] += (p0 + p1) + (p2 + p3);
                uint2 pk; pk.x = pk16(p0, p1); pk.y = pk16(p2, p3);
                *(uint2*)&PX(qn * 16 + ln16, g * 16 + quad * 4) = pk;
            }
        }
    };
    // PV on half hf: reads wave-private P (same-wave ds order: the h1 P
    // writes above cannot pass these reads) + Vls
    auto pv_half = [&](int hf) {
        f16x8 pf[2][2];
        #pragma unroll
        for (int qn = 0; qn < 2; qn++) {
            pf[qn][0] = ld8h(&PX(qn * 16 + ln16, quad * 8));
            pf[qn][1] = ld8h(&PX(qn * 16 + ln16, 32 + quad * 8));
        }
        #pragma unroll
        for (int hg = 0; hg < 4; hg++) {
            f16x8 va0 = ld8h(&VBX(hf, 0, hg * 16 + ln16, quad * 8));
            f16x8 va1 = ld8h(&VBX(hf, 1, hg * 16 + ln16, quad * 8));
            #pragma unroll
            for (int qn = 0; qn < 2; qn++) {
                o[qn][hg] = mfma16h(va0, pf[qn][0], o[qn][hg]);
                o[qn][hg] = mfma16h(va1, pf[qn][1], o[qn][hg]);
            }
        }
    };

    issueK(kv_lo); issueV(kv_lo);
    __syncthreads();                   // prologue: stage 0 resident

    for (int s = 0; s < nst; s++) {
        const int kv0 = kv_lo + s * 128;

        qk_half(0, kv0);               // K h0
        pv_half(0);                    // V h0 (P h0 consumed)
        qk_half(1, kv0 + 64);          // K h1 (last K reader; P overwritten)

        __syncthreads();               // all waves done reading K(s)
        if (s + 1 < nst) issueK(kv0 + 128);  // K(s+1) overlaps PV h1

        pv_half(1);                    // V h1

        __syncthreads();               // V reads done; K(s+1) drained
        if (s + 1 < nst) issueV(kv0 + 128);  // V(s+1) overlaps next QK h0
    }

    #pragma unroll
    for (int qn = 0; qn < 2; qn++) {
        lsum[qn] += __shfl_xor(lsum[qn], 16);
        lsum[qn] += __shfl_xor(lsum[qn], 32);
    }

    if (nch == 1) {
        // single chunk: this IS the final result (path verified in round 2)
        #pragma unroll
        for (int qn = 0; qn < 2; qn++) {
            float inv = 1.f / lsum[qn];
            int q = qmin + qn * 16 + ln16;
            #pragma unroll
            for (int hg = 0; hg < 4; hg++) {
                float4 r;
                r.x = o[qn][hg][0] * inv; r.y = o[qn][hg][1] * inv;
                r.z = o[qn][hg][2] * inv; r.w = o[qn][hg][3] * inv;
                *(float4*)&out[((size_t)(b * L_SEQ + q)) * HEAD + hg * 16 + quad * 4] = r;
            }
        }
        return;
    }

    const size_t base = (size_t)(b * 144 + Sq(qt) + ch);
    #pragma unroll
    for (int qn = 0; qn < 2; qn++) {
        int q_local = wv * 32 + qn * 16 + ln16;
        #pragma unroll
        for (int hg = 0; hg < 4; hg++)
            *(f32x4*)&Opart[base * 8192 + (size_t)q_local * 64 + hg * 16 + quad * 4] = o[qn][hg];
        if (quad == 0)
            lpart[base * 128 + q_local] = lsum[qn];
    }
#undef KBX
#undef VBX
#undef PX
}

// --- Kernel 3: merge partials for qt >= 4 only (qt 0-3 are single-chunk and
// written directly by attn_chunk). <=8 chunks, scalar-branch-guarded loads.
__global__ __launch_bounds__(256) void merge_chunks(
    const float* __restrict__ Opart, const float* __restrict__ lpart,
    float* __restrict__ out)
{
    const int qt = blockIdx.x + 4, qseg = blockIdx.y, b = blockIdx.z;
    const int nch = (qt + 4) >> 2;      // ceil((qt+1)/4)
    const int t = threadIdx.x;
    const size_t obase = (size_t)(b * 144 + Sq(qt)) * 8192;
    const size_t lbase = (size_t)(b * 144 + Sq(qt)) * 128;
    #pragma unroll
    for (int i = 0; i < 2; i++) {
        int idx = i * 256 + t;              // 32 q x 16 h-groups
        int q = qseg * 32 + (idx >> 4), hg = (idx & 15) * 4;
        float L = 0.f, ax = 0.f, ay = 0.f, az = 0.f, aw = 0.f;
        #pragma unroll
        for (int c = 0; c < MAXCH; c++) {
            if (c < nch) {                  // block-uniform scalar branch
                L += lpart[lbase + c * 128 + q];
                const float4 v = *(const float4*)&Opart[obase + (size_t)c * 8192 + q * 64 + hg];
                ax += v.x; ay += v.y; az += v.z; aw += v.w;
            }
        }
        float inv = 1.f / L;
        float4 r; r.x = ax * inv; r.y = ay * inv; r.z = az * inv; r.w = aw * inv;
        *(float4*)&out[((size_t)(b * L_SEQ + qt * 128 + q)) * HEAD + hg] = r;
    }
}

extern "C" void kernel_launch(void* const* d_in, const int* in_sizes, int n_in,
                              void* d_out, int out_size, void* d_ws, size_t ws_size,
                              hipStream_t stream) {
    const float* x  = (const float*)d_in[0];
    const float* Wq = (const float*)d_in[1];
    const float* Wk = (const float*)d_in[2];
    const float* Wv = (const float*)d_in[3];
    float* out = (float*)d_out;

    u16* ws16 = (u16*)d_ws;
    u16* Wt  = ws16;                          // [192][1024] f16 (q|k|v rows)
    u16* qb  = Wt + 3 * HEAD * D_MODEL;       // [4,4096,64] f16
    u16* kb  = qb + 16384 * HEAD;
    u16* vTb = kb + 16384 * HEAD;             // [4,64,4096] f16
    float* Opart = (float*)(vTb + 16384 * HEAD);   // [4*144][8192] f32 = 18.9 MB
    float* lpart = Opart + (size_t)4 * 144 * 8192; // [4*144][128] f32

    conv_w      <<<dim3(16, 3), 256, 0, stream>>>(Wq, Wk, Wv, Wt);
    qkv_proj    <<<dim3(512), 256, 0, stream>>>(x, Wt, qb, kb, vTb);
    attn_chunk  <<<dim3(576), 256, 0, stream>>>(qb, kb, vTb, Opart, lpart, out);
    merge_chunks<<<dim3(NQT - 4, 4, 4), 256, 0, stream>>>(Opart, lpart, out);
}